// Round 11
// baseline (739.828 us; speedup 1.0000x reference)
//
#include <hip/hip_runtime.h>

#define FLT_NEG_MAX -3.402823466e38f
#define NEGC -1000000.0f
#define INV_TAU (1.0f/0.07f)

// B=4 V=4 C=20 H=240 W=320 ; M=500000 N=2000000 ; P=100000 D=64 K=1024
static const long long NN = 2000000LL;

// ws layout (floats):
//  [0..79] seg_sum, [80..83] seg_cnt, [84..163] pred_sum, [164..165] cmg acc
#define WS_KBUF 256                     // 8*1024*64 floats
#define WS_PM   (WS_KBUF + 524288)
#define WS_PS   (WS_PM + 131072)
#define WS_DIAG (WS_PS + 131072)

// mega1 block partition: A = 7813 one-shot gather blocks, B = 4800, C = 512.
// A-blocks are proportionally interleaved with B/C via floor-crossing so the
// latency-bound gathers overlap the BW-bound streaming throughout.
#define NB_A 7813
#define NB_BC 5312
#define NB_T 13125
#define NB_B 4800

__device__ __forceinline__ float wave_sum64(float v) {
  v += __shfl_xor(v, 1, 64);
  v += __shfl_xor(v, 2, 64);
  v += __shfl_xor(v, 4, 64);
  v += __shfl_xor(v, 8, 64);
  v += __shfl_xor(v, 16, 64);
  v += __shfl_xor(v, 32, 64);
  return v;
}
__device__ __forceinline__ float wave_max64(float v) {
  v = fmaxf(v, __shfl_xor(v, 1, 64));
  v = fmaxf(v, __shfl_xor(v, 2, 64));
  v = fmaxf(v, __shfl_xor(v, 4, 64));
  v = fmaxf(v, __shfl_xor(v, 8, 64));
  v = fmaxf(v, __shfl_xor(v, 16, 64));
  v = fmaxf(v, __shfl_xor(v, 32, 64));
  return v;
}
__device__ __forceinline__ float logsig(float x) {
  float z = -x;
  return -(fmaxf(z, 0.0f) + log1pf(__expf(-fabsf(z))));
}

// ---------------------------------------------------------------------------
// mega1 v2: one-shot role-A blocks, A/B interleaved block IDs.
// ---------------------------------------------------------------------------
__global__ __launch_bounds__(256) void mega1(const float* __restrict__ cam3d,
                                             const float* __restrict__ lab3_g,
                                             const int* __restrict__ inv_map,
                                             const int* __restrict__ bidx,
                                             float* __restrict__ out_r3,
                                             const float* __restrict__ cam2d,
                                             const float* __restrict__ lab2_g,
                                             float* __restrict__ out_r2,
                                             const float* __restrict__ fp3,
                                             const float* __restrict__ fp2,
                                             const int* __restrict__ mi3,
                                             const int* __restrict__ mi2,
                                             float* __restrict__ kbuf,
                                             float* __restrict__ acc) {
  __shared__ float smem[5540];   // A: lab3[80] | bins[84] | stage[4][1344]
  const int tid = threadIdx.x;
  const int bid = blockIdx.x;
  const int wid = tid >> 6, lane = tid & 63;

  // proportional interleave: A-block iff floor((bid+1)*NA/NT) > floor(bid*NA/NT)
  const long long lo = ((long long)bid * NB_A) / NB_T;
  const bool isA = (((long long)(bid + 1) * NB_A) / NB_T) > lo;
  const int aid = (int)lo;              // A-index if isA
  const int cid = bid - (int)lo;        // BC-index if !isA  (0..5311)

  if (isA) {
    // ================= role A (one-shot) =================
    float* lab3 = smem;          // 80
    float* bins = smem + 80;     // 84
    float* stage = smem + 164;   // 4 * 1344 (row stride 21)
    if (tid < 80) lab3[tid] = lab3_g[tid];
    if (tid < 84) bins[tid] = 0.0f;
    __syncthreads();

    const long long n = (long long)aid * 256LL + tid;
    const bool active = (n < NN);      // NN % 64 == 0 -> wave-uniform
    float x[20];
    int b = 0;
    if (active) {
      int iv = inv_map[n];
      b = bidx[n];
      const float4* rp = reinterpret_cast<const float4*>(cam3d + (long long)iv * 20LL);
      #pragma unroll
      for (int q = 0; q < 5; ++q) {
        float4 t4 = rp[q];
        x[4*q+0] = t4.x; x[4*q+1] = t4.y; x[4*q+2] = t4.z; x[4*q+3] = t4.w;
      }
    } else {
      #pragma unroll
      for (int c = 0; c < 20; ++c) x[c] = 0.0f;
    }
    // segment sums: one butterfly flush per wave (batch_idx sorted -> uni
    // except at <=3 boundary waves)
    int b0 = __shfl(b, 0, 64);
    bool uni = __all(active) && __all(b == b0);
    if (uni) {
      #pragma unroll
      for (int c = 0; c < 20; ++c) {
        float v = wave_sum64(x[c]);
        if (lane == 0) atomicAdd(&bins[b0 * 20 + c], v);
      }
      if (lane == 0) atomicAdd(&bins[80 + b0], 64.0f);
    } else if (active) {
      #pragma unroll
      for (int c = 0; c < 20; ++c) atomicAdd(&bins[b * 20 + c], x[c]);
      atomicAdd(&bins[80 + b], 1.0f);
    }
    // masked softmax
    if (active) {
      float mx = FLT_NEG_MAX;
      #pragma unroll
      for (int c = 0; c < 20; ++c) {
        x[c] += (1.0f - lab3[b * 20 + c]) * NEGC;
        mx = fmaxf(mx, x[c]);
      }
      float s = 0.0f;
      #pragma unroll
      for (int c = 0; c < 20; ++c) { x[c] = __expf(x[c] - mx); s += x[c]; }
      float is = 1.0f / s;
      #pragma unroll
      for (int c = 0; c < 20; ++c) x[c] *= is;
    }
    // coalesced write via LDS stage (out_r3 only 4B-aligned)
    #pragma unroll
    for (int c = 0; c < 20; ++c) stage[wid * 1344 + lane * 21 + c] = x[c];
    __syncthreads();                   // stage-write -> stage-read (+ bins stable)
    if (active) {                      // wave-uniform; active wave => full 64 rows
      const long long nw = (long long)aid * 256LL + (long long)wid * 64LL;
      #pragma unroll
      for (int j = 0; j < 20; ++j) {
        int idx = lane + 64 * j;
        int rl = idx / 20;
        int cc = idx - rl * 20;
        __builtin_nontemporal_store(stage[wid * 1344 + rl * 21 + cc],
                                    &out_r3[nw * 20LL + idx]);
      }
    }
    if (tid < 84) atomicAdd(&acc[tid], bins[tid]);

  } else if (cid < NB_B) {
    // ================= role B =================
    const int rb = cid;                // 4800 = B * H * (W/64)
    const int b = rb / 1200;
    const int rem = rb - b * 1200;
    const int h = rem / 5;
    const int wt = rem - h * 5;
    const int wl = tid >> 2, v = tid & 3;
    const int w = wt * 64 + wl;
    float* bins2 = smem;               // 20
    if (tid < 20) bins2[tid] = 0.0f;
    __syncthreads();
    const float* inb = cam2d + ((long long)(b * 4 + v) * 20LL) * 76800LL
                     + (long long)h * 320 + w;
    float x[20];
    #pragma unroll
    for (int c = 0; c < 20; ++c) x[c] = inb[(long long)c * 76800LL];
    // predict sums on RAW values
    #pragma unroll
    for (int c = 0; c < 20; ++c) {
      float s = wave_sum64(x[c]);
      if (lane == 0) atomicAdd(&bins2[c], s);
    }
    // masked softmax
    float mx = FLT_NEG_MAX;
    #pragma unroll
    for (int c = 0; c < 20; ++c) {
      x[c] += (1.0f - lab2_g[b * 20 + c]) * NEGC;
      mx = fmaxf(mx, x[c]);
    }
    float s = 0.0f;
    #pragma unroll
    for (int c = 0; c < 20; ++c) { x[c] = __expf(x[c] - mx); s += x[c]; }
    float is = 1.0f / s;
    // direct store: addr = base + tid (lane-consecutive, coalesced)
    #pragma unroll
    for (int c = 0; c < 20; ++c)
      __builtin_nontemporal_store(x[c] * is,
          &out_r2[(((long long)(b * 20 + c) * 240 + h) * 320 + w) * 4 + v]);
    __syncthreads();
    if (tid < 20) atomicAdd(&acc[84 + b * 20 + tid], bins2[tid]);

  } else {
    // ================= role C =================
    int g = (cid - NB_B) * 256 + tid;  // 8192 rows * 16 f4
    int row = g >> 4;
    int d4 = g & 15;
    int pair = row >> 10;
    int l = pair >> 2, b = pair & 3;
    int i = row & 1023;
    int idx = l ? mi2[b * 1024 + i] : mi3[b * 1024 + i];
    const float* src = l ? fp2 : fp3;
    const float4* s4 = reinterpret_cast<const float4*>(src + ((long long)b * 100000 + idx) * 64LL);
    reinterpret_cast<float4*>(kbuf)[(long long)row * 16 + d4] = s4[d4];
  }
}

// ---------------------------------------------------------------------------
// Kernel D: cmg logits + partial row-LSE (lane=q-col in VGPRs, k rows stream
// via wave-uniform loads; butterfly per row).
// ---------------------------------------------------------------------------
__global__ __launch_bounds__(256) void kD(const float* __restrict__ kbuf,
                                          const float* __restrict__ fd2,
                                          const float* __restrict__ fd3,
                                          const int* __restrict__ mi3,
                                          const int* __restrict__ mi2,
                                          float* __restrict__ pm,
                                          float* __restrict__ ps,
                                          float* __restrict__ diag) {
  const int wglob = blockIdx.x * 4 + (threadIdx.x >> 6);
  const int lane = threadIdx.x & 63;
  const int pair = wglob >> 9;
  const int cb = (wglob >> 5) & 15;
  const int rb = wglob & 31;
  const int l = pair >> 2, b = pair & 3;
  const int colg = cb * 64 + lane;
  const int qi = l ? mi2[b * 1024 + colg] : mi3[b * 1024 + colg];
  const float* fq = l ? fd3 : fd2;
  const float4* q4 = reinterpret_cast<const float4*>(fq + ((long long)b * 100000 + qi) * 64LL);
  float4 q[16];
  #pragma unroll
  for (int d = 0; d < 16; ++d) q[d] = q4[d];
  const float* kbase = kbuf + ((long long)pair * 1024 + rb * 32) * 64LL;
  float m_keep = 0.0f, s_keep = 0.0f;
  for (int r = 0; r < 32; ++r) {
    const float4* kr = reinterpret_cast<const float4*>(kbase + r * 64);
    float a0 = 0, a1 = 0, a2 = 0, a3 = 0;
    #pragma unroll
    for (int d = 0; d < 16; ++d) {
      float4 kv = kr[d];
      a0 = fmaf(kv.x, q[d].x, a0);
      a1 = fmaf(kv.y, q[d].y, a1);
      a2 = fmaf(kv.z, q[d].z, a2);
      a3 = fmaf(kv.w, q[d].w, a3);
    }
    float vlog = (a0 + a1 + a2 + a3) * INV_TAU;
    int rowg = rb * 32 + r;
    if (colg == rowg) diag[pair * 1024 + rowg] = vlog;
    float mx = wave_max64(vlog);
    float se = wave_sum64(__expf(vlog - mx));
    if (lane == r) { m_keep = mx; s_keep = se; }
  }
  if (lane < 32) {
    int off = (pair * 16 + cb) * 1024 + rb * 32 + lane;
    pm[off] = m_keep;
    ps[off] = s_keep;
  }
}

// ---------------------------------------------------------------------------
// Kernel E: merge col-block partials; r = diag - LSE; sum -> acc[164+l]
// ---------------------------------------------------------------------------
__global__ __launch_bounds__(256) void kE(const float* __restrict__ pm,
                                          const float* __restrict__ ps,
                                          const float* __restrict__ diag,
                                          float* __restrict__ acc) {
  const int row = blockIdx.x * 256 + threadIdx.x;
  const int pair = row >> 10;
  const int rl = row & 1023;
  const int l = pair >> 2;
  float m = FLT_NEG_MAX, s = 0.0f;
  #pragma unroll
  for (int cb = 0; cb < 16; ++cb) {
    float mm = pm[(pair * 16 + cb) * 1024 + rl];
    float ss = ps[(pair * 16 + cb) * 1024 + rl];
    if (mm > m) { s = s * __expf(m - mm) + ss; m = mm; }
    else        { s += ss * __expf(mm - m); }
  }
  float r = diag[row] - (m + __logf(s));
  float t = wave_sum64(r);
  __shared__ float wsum[4];
  if ((threadIdx.x & 63) == 0) wsum[threadIdx.x >> 6] = t;
  __syncthreads();
  if (threadIdx.x == 0)
    atomicAdd(&acc[164 + l], wsum[0] + wsum[1] + wsum[2] + wsum[3]);
}

// ---------------------------------------------------------------------------
// Kernel F: final scalar loss
// ---------------------------------------------------------------------------
__global__ __launch_bounds__(256) void kF(const float* __restrict__ acc,
                                          const float* __restrict__ lab3,
                                          const float* __restrict__ lab2,
                                          float* __restrict__ out_loss) {
  const int t = threadIdx.x;
  float term = 0.0f;
  if (t < 80) {
    int b = t / 20;
    float x = acc[t] / acc[80 + b];
    float y = lab3[t];
    term = y * logsig(x) + (1.0f - y) * logsig(-x);
  } else if (t < 160) {
    int i = t - 80;
    float x = acc[84 + i] * (1.0f / 307200.0f);
    float y = lab2[i];
    term = y * logsig(x) + (1.0f - y) * logsig(-x);
  }
  float tsum = wave_sum64(term);
  __shared__ float wsum[4];
  if ((t & 63) == 0) wsum[t >> 6] = tsum;
  __syncthreads();
  if (t == 0) {
    float total = wsum[0] + wsum[1] + wsum[2] + wsum[3];
    float margin = -total / 80.0f;
    float cmg = -(acc[164] + acc[165]) / 1024.0f;
    out_loss[0] = margin + cmg;
  }
}

// ---------------------------------------------------------------------------
extern "C" void kernel_launch(void* const* d_in, const int* in_sizes, int n_in,
                              void* d_out, int out_size, void* d_ws, size_t ws_size,
                              hipStream_t stream) {
  (void)in_sizes; (void)n_in; (void)out_size; (void)ws_size;
  const float* cam3d = (const float*)d_in[0];
  const float* cam2d = (const float*)d_in[1];
  const float* fp3   = (const float*)d_in[2];
  const float* fd2   = (const float*)d_in[3];
  const float* fp2   = (const float*)d_in[4];
  const float* fd3   = (const float*)d_in[5];
  const float* lab3  = (const float*)d_in[6];
  const float* lab2  = (const float*)d_in[7];
  const int* invm    = (const int*)d_in[8];
  const int* bidx    = (const int*)d_in[9];
  const int* mi3     = (const int*)d_in[10];
  const int* mi2     = (const int*)d_in[11];

  float* out      = (float*)d_out;
  float* out_loss = out;
  float* out_r3   = out + 1;
  float* out_r2   = out + 1 + 40000000LL;

  float* acc  = (float*)d_ws;
  float* kbuf = acc + WS_KBUF;
  float* pm   = acc + WS_PM;
  float* psb  = acc + WS_PS;
  float* diag = acc + WS_DIAG;

  hipMemsetAsync(d_ws, 0, 1024, stream);

  mega1<<<NB_T, 256, 0, stream>>>(cam3d, lab3, invm, bidx, out_r3,
                                  cam2d, lab2, out_r2,
                                  fp3, fp2, mi3, mi2, kbuf, acc);
  kD<<<1024, 256, 0, stream>>>(kbuf, fd2, fd3, mi3, mi2, pm, psb, diag);
  kE<<<32, 256, 0, stream>>>(pm, psb, diag, acc);
  kF<<<1, 256, 0, stream>>>(acc, lab3, lab2, out_loss);
}

// Round 12
// 686.060 us; speedup vs baseline: 1.0784x; 1.0784x over previous
//
#include <hip/hip_runtime.h>

#define FLT_NEG_MAX -3.402823466e38f
#define NEGC -1000000.0f
#define INV_TAU (1.0f/0.07f)

// B=4 V=4 C=20 H=240 W=320 ; M=500000 N=2000000 ; P=100000 D=64 K=1024
static const long long NN = 2000000LL;

// ws layout (floats):
//  [0..79] seg_sum, [80..83] seg_cnt, [84..163] pred_sum, [164..165] cmg acc
#define WS_KBUF 256                     // 8*1024*64 floats
#define WS_PM   (WS_KBUF + 524288)
#define WS_PS   (WS_PM + 131072)
#define WS_DIAG (WS_PS + 131072)

// mega1 block partition (v1 layout, best measured)
#define NB_A 1792
#define NB_B 4800
#define NB_C 512

__device__ __forceinline__ float wave_sum64(float v) {
  v += __shfl_xor(v, 1, 64);
  v += __shfl_xor(v, 2, 64);
  v += __shfl_xor(v, 4, 64);
  v += __shfl_xor(v, 8, 64);
  v += __shfl_xor(v, 16, 64);
  v += __shfl_xor(v, 32, 64);
  return v;
}
__device__ __forceinline__ float wave_max64(float v) {
  v = fmaxf(v, __shfl_xor(v, 1, 64));
  v = fmaxf(v, __shfl_xor(v, 2, 64));
  v = fmaxf(v, __shfl_xor(v, 4, 64));
  v = fmaxf(v, __shfl_xor(v, 8, 64));
  v = fmaxf(v, __shfl_xor(v, 16, 64));
  v = fmaxf(v, __shfl_xor(v, 32, 64));
  return v;
}
__device__ __forceinline__ float logsig(float x) {
  float z = -x;
  return -(fmaxf(z, 0.0f) + log1pf(__expf(-fabsf(z))));
}

// ---------------------------------------------------------------------------
// mega1 v3: v1 grid-stride structure, but role A's K-loop is BARRIER-FREE.
// The LDS stage is wave-private (indexed by wid), so ds_write->ds_read needs
// only lgkmcnt (compiler-inserted), not __syncthreads. Waves free-run in
// staggered phases -> CU-level outstanding-gather pool never drains.
// Explicit next-iteration index prefetch pipelines the idx->gather chain.
// ---------------------------------------------------------------------------
__global__ __launch_bounds__(256) void mega1(const float* __restrict__ cam3d,
                                             const float* __restrict__ lab3_g,
                                             const int* __restrict__ inv_map,
                                             const int* __restrict__ bidx,
                                             float* __restrict__ out_r3,
                                             const float* __restrict__ cam2d,
                                             const float* __restrict__ lab2_g,
                                             float* __restrict__ out_r2,
                                             const float* __restrict__ fp3,
                                             const float* __restrict__ fp2,
                                             const int* __restrict__ mi3,
                                             const int* __restrict__ mi2,
                                             float* __restrict__ kbuf,
                                             float* __restrict__ acc) {
  __shared__ float smem[5540];   // A: lab3[80] | bins[84] | stage[4][1344]
  const int tid = threadIdx.x;
  const int bid = blockIdx.x;
  const int wid = tid >> 6, lane = tid & 63;

  if (bid < NB_A) {
    // ================= role A (barrier-free loop) =================
    float* lab3 = smem;          // 80
    float* bins = smem + 80;     // 84
    float* stage = smem + 164;   // 4 * 1344 (row stride 21)
    if (tid < 80) lab3[tid] = lab3_g[tid];
    if (tid < 84) bins[tid] = 0.0f;
    __syncthreads();             // lab3/bins ready (only barrier before epilogue)

    float racc[20];
    #pragma unroll
    for (int c = 0; c < 20; ++c) racc[c] = 0.0f;
    float rcnt = 0.0f;
    int rb_cur = -1;

    const long long stride = (long long)NB_A * 256LL;
    long long n = (long long)bid * 256LL + tid;
    bool active = (n < NN);            // NN % 64 == 0 -> wave-uniform
    int iv = 0, b = 0;
    if (active) { iv = inv_map[n]; b = bidx[n]; }

    while (active) {
      // gather current rows (5 outstanding dwordx4 per lane)
      float x[20];
      const float4* rp = reinterpret_cast<const float4*>(cam3d + (long long)iv * 20LL);
      #pragma unroll
      for (int q = 0; q < 5; ++q) {
        float4 t4 = rp[q];
        x[4*q+0] = t4.x; x[4*q+1] = t4.y; x[4*q+2] = t4.z; x[4*q+3] = t4.w;
      }
      // prefetch next iteration's indices (breaks idx->gather serial chain)
      const long long n2 = n + stride;
      const bool active2 = (n2 < NN);
      int iv2 = 0, b2 = 0;
      if (active2) { iv2 = inv_map[n2]; b2 = bidx[n2]; }

      // segment sums: register path (batch_idx sorted -> rare flushes)
      int b0 = __shfl(b, 0, 64);
      bool uni = __all(b == b0);
      if (uni) {
        if (b0 != rb_cur) {
          if (rb_cur >= 0) {
            #pragma unroll
            for (int c = 0; c < 20; ++c) {
              float v = wave_sum64(racc[c]);
              if (lane == 0) atomicAdd(&bins[rb_cur * 20 + c], v);
              racc[c] = 0.0f;
            }
            if (lane == 0) atomicAdd(&bins[80 + rb_cur], rcnt * 64.0f);
            rcnt = 0.0f;
          }
          rb_cur = b0;
        }
        #pragma unroll
        for (int c = 0; c < 20; ++c) racc[c] += x[c];
        rcnt += 1.0f;
      } else {
        #pragma unroll
        for (int c = 0; c < 20; ++c) atomicAdd(&bins[b * 20 + c], x[c]);
        atomicAdd(&bins[80 + b], 1.0f);
      }
      // masked softmax
      {
        float mx = FLT_NEG_MAX;
        #pragma unroll
        for (int c = 0; c < 20; ++c) {
          x[c] += (1.0f - lab3[b * 20 + c]) * NEGC;
          mx = fmaxf(mx, x[c]);
        }
        float s = 0.0f;
        #pragma unroll
        for (int c = 0; c < 20; ++c) { x[c] = __expf(x[c] - mx); s += x[c]; }
        float is = 1.0f / s;
        #pragma unroll
        for (int c = 0; c < 20; ++c) x[c] *= is;
      }
      // wave-private LDS transpose (NO barrier: same-wave ds_write->ds_read
      // ordered by lgkmcnt, compiler-inserted). stride 21 = conflict-free.
      #pragma unroll
      for (int c = 0; c < 20; ++c) stage[wid * 1344 + lane * 21 + c] = x[c];
      {
        const long long nw = n - lane;     // wave's first row
        #pragma unroll
        for (int j = 0; j < 20; ++j) {
          int idx = lane + 64 * j;
          int rl = idx / 20;
          int cc = idx - rl * 20;
          __builtin_nontemporal_store(stage[wid * 1344 + rl * 21 + cc],
                                      &out_r3[nw * 20LL + idx]);
        }
      }
      n = n2; iv = iv2; b = b2; active = active2;
    }
    // final register flush
    if (rb_cur >= 0) {
      #pragma unroll
      for (int c = 0; c < 20; ++c) {
        float v = wave_sum64(racc[c]);
        if (lane == 0) atomicAdd(&bins[rb_cur * 20 + c], v);
      }
      if (lane == 0) atomicAdd(&bins[80 + rb_cur], rcnt * 64.0f);
    }
    __syncthreads();                    // all waves' bins atomics done
    if (tid < 84) atomicAdd(&acc[tid], bins[tid]);

  } else if (bid < NB_A + NB_B) {
    // ================= role B =================
    const int rb = bid - NB_A;         // 4800 = B * H * (W/64)
    const int b = rb / 1200;
    const int rem = rb - b * 1200;
    const int h = rem / 5;
    const int wt = rem - h * 5;
    const int wl = tid >> 2, v = tid & 3;
    const int w = wt * 64 + wl;
    float* bins2 = smem;               // 20
    if (tid < 20) bins2[tid] = 0.0f;
    __syncthreads();
    const float* inb = cam2d + ((long long)(b * 4 + v) * 20LL) * 76800LL
                     + (long long)h * 320 + w;
    float x[20];
    #pragma unroll
    for (int c = 0; c < 20; ++c) x[c] = inb[(long long)c * 76800LL];
    // predict sums on RAW values
    #pragma unroll
    for (int c = 0; c < 20; ++c) {
      float s = wave_sum64(x[c]);
      if (lane == 0) atomicAdd(&bins2[c], s);
    }
    // masked softmax
    float mx = FLT_NEG_MAX;
    #pragma unroll
    for (int c = 0; c < 20; ++c) {
      x[c] += (1.0f - lab2_g[b * 20 + c]) * NEGC;
      mx = fmaxf(mx, x[c]);
    }
    float s = 0.0f;
    #pragma unroll
    for (int c = 0; c < 20; ++c) { x[c] = __expf(x[c] - mx); s += x[c]; }
    float is = 1.0f / s;
    // direct store: addr = base + tid (lane-consecutive, coalesced)
    #pragma unroll
    for (int c = 0; c < 20; ++c)
      __builtin_nontemporal_store(x[c] * is,
          &out_r2[(((long long)(b * 20 + c) * 240 + h) * 320 + w) * 4 + v]);
    __syncthreads();
    if (tid < 20) atomicAdd(&acc[84 + b * 20 + tid], bins2[tid]);

  } else {
    // ================= role C =================
    int g = (bid - NB_A - NB_B) * 256 + tid;   // 8192 rows * 16 f4
    int row = g >> 4;
    int d4 = g & 15;
    int pair = row >> 10;
    int l = pair >> 2, b = pair & 3;
    int i = row & 1023;
    int idx = l ? mi2[b * 1024 + i] : mi3[b * 1024 + i];
    const float* src = l ? fp2 : fp3;
    const float4* s4 = reinterpret_cast<const float4*>(src + ((long long)b * 100000 + idx) * 64LL);
    reinterpret_cast<float4*>(kbuf)[(long long)row * 16 + d4] = s4[d4];
  }
}

// ---------------------------------------------------------------------------
// Kernel D: cmg logits + partial row-LSE (lane=q-col in VGPRs, k rows stream
// via wave-uniform loads; butterfly per row).
// ---------------------------------------------------------------------------
__global__ __launch_bounds__(256) void kD(const float* __restrict__ kbuf,
                                          const float* __restrict__ fd2,
                                          const float* __restrict__ fd3,
                                          const int* __restrict__ mi3,
                                          const int* __restrict__ mi2,
                                          float* __restrict__ pm,
                                          float* __restrict__ ps,
                                          float* __restrict__ diag) {
  const int wglob = blockIdx.x * 4 + (threadIdx.x >> 6);
  const int lane = threadIdx.x & 63;
  const int pair = wglob >> 9;
  const int cb = (wglob >> 5) & 15;
  const int rb = wglob & 31;
  const int l = pair >> 2, b = pair & 3;
  const int colg = cb * 64 + lane;
  const int qi = l ? mi2[b * 1024 + colg] : mi3[b * 1024 + colg];
  const float* fq = l ? fd3 : fd2;
  const float4* q4 = reinterpret_cast<const float4*>(fq + ((long long)b * 100000 + qi) * 64LL);
  float4 q[16];
  #pragma unroll
  for (int d = 0; d < 16; ++d) q[d] = q4[d];
  const float* kbase = kbuf + ((long long)pair * 1024 + rb * 32) * 64LL;
  float m_keep = 0.0f, s_keep = 0.0f;
  for (int r = 0; r < 32; ++r) {
    const float4* kr = reinterpret_cast<const float4*>(kbase + r * 64);
    float a0 = 0, a1 = 0, a2 = 0, a3 = 0;
    #pragma unroll
    for (int d = 0; d < 16; ++d) {
      float4 kv = kr[d];
      a0 = fmaf(kv.x, q[d].x, a0);
      a1 = fmaf(kv.y, q[d].y, a1);
      a2 = fmaf(kv.z, q[d].z, a2);
      a3 = fmaf(kv.w, q[d].w, a3);
    }
    float vlog = (a0 + a1 + a2 + a3) * INV_TAU;
    int rowg = rb * 32 + r;
    if (colg == rowg) diag[pair * 1024 + rowg] = vlog;
    float mx = wave_max64(vlog);
    float se = wave_sum64(__expf(vlog - mx));
    if (lane == r) { m_keep = mx; s_keep = se; }
  }
  if (lane < 32) {
    int off = (pair * 16 + cb) * 1024 + rb * 32 + lane;
    pm[off] = m_keep;
    ps[off] = s_keep;
  }
}

// ---------------------------------------------------------------------------
// Kernel E: merge col-block partials; r = diag - LSE; sum -> acc[164+l]
// ---------------------------------------------------------------------------
__global__ __launch_bounds__(256) void kE(const float* __restrict__ pm,
                                          const float* __restrict__ ps,
                                          const float* __restrict__ diag,
                                          float* __restrict__ acc) {
  const int row = blockIdx.x * 256 + threadIdx.x;
  const int pair = row >> 10;
  const int rl = row & 1023;
  const int l = pair >> 2;
  float m = FLT_NEG_MAX, s = 0.0f;
  #pragma unroll
  for (int cb = 0; cb < 16; ++cb) {
    float mm = pm[(pair * 16 + cb) * 1024 + rl];
    float ss = ps[(pair * 16 + cb) * 1024 + rl];
    if (mm > m) { s = s * __expf(m - mm) + ss; m = mm; }
    else        { s += ss * __expf(mm - m); }
  }
  float r = diag[row] - (m + __logf(s));
  float t = wave_sum64(r);
  __shared__ float wsum[4];
  if ((threadIdx.x & 63) == 0) wsum[threadIdx.x >> 6] = t;
  __syncthreads();
  if (threadIdx.x == 0)
    atomicAdd(&acc[164 + l], wsum[0] + wsum[1] + wsum[2] + wsum[3]);
}

// ---------------------------------------------------------------------------
// Kernel F: final scalar loss
// ---------------------------------------------------------------------------
__global__ __launch_bounds__(256) void kF(const float* __restrict__ acc,
                                          const float* __restrict__ lab3,
                                          const float* __restrict__ lab2,
                                          float* __restrict__ out_loss) {
  const int t = threadIdx.x;
  float term = 0.0f;
  if (t < 80) {
    int b = t / 20;
    float x = acc[t] / acc[80 + b];
    float y = lab3[t];
    term = y * logsig(x) + (1.0f - y) * logsig(-x);
  } else if (t < 160) {
    int i = t - 80;
    float x = acc[84 + i] * (1.0f / 307200.0f);
    float y = lab2[i];
    term = y * logsig(x) + (1.0f - y) * logsig(-x);
  }
  float tsum = wave_sum64(term);
  __shared__ float wsum[4];
  if ((t & 63) == 0) wsum[t >> 6] = tsum;
  __syncthreads();
  if (t == 0) {
    float total = wsum[0] + wsum[1] + wsum[2] + wsum[3];
    float margin = -total / 80.0f;
    float cmg = -(acc[164] + acc[165]) / 1024.0f;
    out_loss[0] = margin + cmg;
  }
}

// ---------------------------------------------------------------------------
extern "C" void kernel_launch(void* const* d_in, const int* in_sizes, int n_in,
                              void* d_out, int out_size, void* d_ws, size_t ws_size,
                              hipStream_t stream) {
  (void)in_sizes; (void)n_in; (void)out_size; (void)ws_size;
  const float* cam3d = (const float*)d_in[0];
  const float* cam2d = (const float*)d_in[1];
  const float* fp3   = (const float*)d_in[2];
  const float* fd2   = (const float*)d_in[3];
  const float* fp2   = (const float*)d_in[4];
  const float* fd3   = (const float*)d_in[5];
  const float* lab3  = (const float*)d_in[6];
  const float* lab2  = (const float*)d_in[7];
  const int* invm    = (const int*)d_in[8];
  const int* bidx    = (const int*)d_in[9];
  const int* mi3     = (const int*)d_in[10];
  const int* mi2     = (const int*)d_in[11];

  float* out      = (float*)d_out;
  float* out_loss = out;
  float* out_r3   = out + 1;
  float* out_r2   = out + 1 + 40000000LL;

  float* acc  = (float*)d_ws;
  float* kbuf = acc + WS_KBUF;
  float* pm   = acc + WS_PM;
  float* psb  = acc + WS_PS;
  float* diag = acc + WS_DIAG;

  hipMemsetAsync(d_ws, 0, 1024, stream);

  mega1<<<NB_A + NB_B + NB_C, 256, 0, stream>>>(cam3d, lab3, invm, bidx, out_r3,
                                                cam2d, lab2, out_r2,
                                                fp3, fp2, mi3, mi2, kbuf, acc);
  kD<<<1024, 256, 0, stream>>>(kbuf, fd2, fd3, mi3, mi2, pm, psb, diag);
  kE<<<32, 256, 0, stream>>>(pm, psb, diag, acc);
  kF<<<1, 256, 0, stream>>>(acc, lab3, lab2, out_loss);
}